// Round 7
// baseline (110.424 us; speedup 1.0000x reference)
//
#include <hip/hip_runtime.h>
#include <hip/hip_bf16.h>

// ContrastiveLoss: N=8192, D=256, NUM_IDS=1000, MARGIN=0.3
// R7: label-free GEMM epilogue (3 VALU/elem) via algebraic split:
//   loss*N = sum_all negv(s) + sum_{same-label pairs} [posv(s) - negv(s)]
// Term 1: R6's pipelined LDS GEMM (counted vmcnt, 3-buf), weight 2 off-diag /
// 1 diag (full-block sum = 2*upper + diag by symmetry). Term 2: sparse
// per-label pair kernel recomputing bf16 dots (~67K pairs).

#define MARGINF 0.3f

typedef __attribute__((ext_vector_type(8))) short short8x;    // 8 bf16 (4 VGPRs)
typedef __attribute__((ext_vector_type(16))) float f32x16;    // 16 fp32 acc

// ---------- round-to-nearest-even f32 -> bf16 bits ----------
__device__ __forceinline__ unsigned short f2bf(float f) {
    unsigned int u = __float_as_uint(f);
    unsigned int r = (u + 0x7fffu + ((u >> 16) & 1u)) >> 16;
    return (unsigned short)r;
}

// ---------- pass 1: fp32 -> bf16 row-major convert (verified R1/R2/R6) ----------
__global__ void __launch_bounds__(256) convert_k(const float* __restrict__ x,
                                                 unsigned short* __restrict__ xb) {
    int i = blockIdx.x * 256 + threadIdx.x;          // 0 .. 262143
    const float4* p = reinterpret_cast<const float4*>(x) + (size_t)i * 2;
    float4 a = p[0];
    float4 b = p[1];
    short8x o;
    o[0] = (short)f2bf(a.x); o[1] = (short)f2bf(a.y);
    o[2] = (short)f2bf(a.z); o[3] = (short)f2bf(a.w);
    o[4] = (short)f2bf(b.x); o[5] = (short)f2bf(b.y);
    o[6] = (short)f2bf(b.z); o[7] = (short)f2bf(b.w);
    reinterpret_cast<short8x*>(xb)[i] = o;
}

// ---------- pass 2: pipelined LDS GEMM + label-free neg-sum epilogue ----------
// 128^2 tile, 4 waves (2x2), BK=32, 3 rotating LDS bufs, counted vmcnt (R6).
__global__ void __launch_bounds__(256, 3) gemm_loss_k(const unsigned short* __restrict__ xb,
                                                      double* __restrict__ partials) {
    // ---- 1D upper-triangle decode: p -> (bi <= bj), 64x64 tile grid ----
    const int p = blockIdx.x;
    int bi = (int)(64.5f - sqrtf(64.5f * 64.5f - 2.0f * (float)p));
    if (bi < 0) bi = 0;
    if (bi > 63) bi = 63;
    while (bi > 0 && (bi * (129 - bi)) / 2 > p) --bi;
    while (((bi + 1) * (128 - bi)) / 2 <= p) ++bi;
    const int bj = bi + (p - (bi * (129 - bi)) / 2);

    __shared__ __align__(16) char ldsb[3 * 16384];
    __shared__ float redbuf[4];

    const int tid  = threadIdx.x;
    const int lane = tid & 63;
    const int wid  = tid >> 6;       // 0..3
    const int wr   = wid >> 1;       // wave row (0..1)
    const int wc   = wid & 1;        // wave col (0..1)

    const char* aBase = (const char*)(xb + (size_t)bi * 128 * 256);
    const char* bBase = (const char*)(xb + (size_t)bj * 128 * 256);

    // ---- stage addressing: thread t writes LDS byte i*4096 + t*16 ----
    // row r = i*64 + (t>>2); stored chunk c' = t&3; source chunk = c' ^ ((r>>1)&3)
    const int srow0  = wid * 16 + (lane >> 2);
    const int schunk = (((lane & 3) ^ ((lane >> 3) & 3))) << 4;

    // ---- ds_read offsets: frag row r = base + (lane&31); swz = ((lane&31)>>1)&3
    const int l31 = lane & 31;
    const int hi  = lane >> 5;
    const int swz = (l31 >> 1) & 3;
    int offA[2][2], offB[2][2];
#pragma unroll
    for (int fm = 0; fm < 2; ++fm)
#pragma unroll
        for (int ks = 0; ks < 2; ++ks)
            offA[fm][ks] = (wr * 64 + fm * 32 + l31) * 64 + ((((ks << 1) | hi) ^ swz) << 4);
#pragma unroll
    for (int fn = 0; fn < 2; ++fn)
#pragma unroll
        for (int ks = 0; ks < 2; ++ks)
            offB[fn][ks] = 8192 + (wc * 64 + fn * 32 + l31) * 64 + ((((ks << 1) | hi) ^ swz) << 4);

    f32x16 acc00 = {}, acc01 = {}, acc10 = {}, acc11 = {};

#define STAGE_KT(BUF, T) do {                                                        \
    _Pragma("unroll")                                                                \
    for (int i_ = 0; i_ < 2; ++i_) {                                                 \
        const int r_ = i_ * 64 + srow0;                                              \
        const char* sa_ = aBase + (size_t)r_ * 512 + (T) * 64 + schunk;              \
        const char* sb_ = bBase + (size_t)r_ * 512 + (T) * 64 + schunk;              \
        __builtin_amdgcn_global_load_lds(                                            \
            (const __attribute__((address_space(1))) unsigned int*)sa_,              \
            (__attribute__((address_space(3))) unsigned int*)(ldsb + (BUF) * 16384 + i_ * 4096 + wid * 1024), \
            16, 0, 0);                                                               \
        __builtin_amdgcn_global_load_lds(                                            \
            (const __attribute__((address_space(1))) unsigned int*)sb_,              \
            (__attribute__((address_space(3))) unsigned int*)(ldsb + (BUF) * 16384 + 8192 + i_ * 4096 + wid * 1024), \
            16, 0, 0);                                                               \
    }                                                                                \
} while (0)

#define GEMM_ITER(T, BUF, VMSTR, DOSTAGE) do {                                       \
    asm volatile("s_waitcnt vmcnt(" VMSTR ")" ::: "memory");                         \
    __builtin_amdgcn_s_barrier();                 /* KT T visible to all waves */    \
    const char* lb_ = ldsb + (BUF) * 16384;                                          \
    short8x a0k0 = *(const short8x*)(lb_ + offA[0][0]);                              \
    short8x a1k0 = *(const short8x*)(lb_ + offA[1][0]);                              \
    short8x b0k0 = *(const short8x*)(lb_ + offB[0][0]);                              \
    short8x b1k0 = *(const short8x*)(lb_ + offB[1][0]);                              \
    short8x a0k1 = *(const short8x*)(lb_ + offA[0][1]);                              \
    short8x a1k1 = *(const short8x*)(lb_ + offA[1][1]);                              \
    short8x b0k1 = *(const short8x*)(lb_ + offB[0][1]);                              \
    short8x b1k1 = *(const short8x*)(lb_ + offB[1][1]);                              \
    asm volatile("s_waitcnt lgkmcnt(0)" ::: "memory");                               \
    __builtin_amdgcn_sched_barrier(0);                                               \
    __builtin_amdgcn_s_barrier();                 /* all waves done reading BUF */   \
    if (DOSTAGE) STAGE_KT(BUF, (T) + 3);          /* refill freed buffer */          \
    __builtin_amdgcn_s_setprio(1);                                                   \
    acc00 = __builtin_amdgcn_mfma_f32_32x32x16_bf16(a0k0, b0k0, acc00, 0, 0, 0);     \
    acc01 = __builtin_amdgcn_mfma_f32_32x32x16_bf16(a0k0, b1k0, acc01, 0, 0, 0);     \
    acc10 = __builtin_amdgcn_mfma_f32_32x32x16_bf16(a1k0, b0k0, acc10, 0, 0, 0);     \
    acc11 = __builtin_amdgcn_mfma_f32_32x32x16_bf16(a1k0, b1k0, acc11, 0, 0, 0);     \
    acc00 = __builtin_amdgcn_mfma_f32_32x32x16_bf16(a0k1, b0k1, acc00, 0, 0, 0);     \
    acc01 = __builtin_amdgcn_mfma_f32_32x32x16_bf16(a0k1, b1k1, acc01, 0, 0, 0);     \
    acc10 = __builtin_amdgcn_mfma_f32_32x32x16_bf16(a1k1, b0k1, acc10, 0, 0, 0);     \
    acc11 = __builtin_amdgcn_mfma_f32_32x32x16_bf16(a1k1, b1k1, acc11, 0, 0, 0);     \
    __builtin_amdgcn_s_setprio(0);                                                   \
} while (0)

    // prologue: stage KT0..KT2 (12 loads in flight per thread)
    STAGE_KT(0, 0);
    STAGE_KT(1, 1);
    STAGE_KT(2, 2);

    // 8 K-tiles; vmcnt ladder keeps 2 tiles in flight until drain
    GEMM_ITER(0, 0, "8", 1);
    GEMM_ITER(1, 1, "8", 1);
    GEMM_ITER(2, 2, "8", 1);
    GEMM_ITER(3, 0, "8", 1);
    GEMM_ITER(4, 1, "8", 1);
    GEMM_ITER(5, 2, "8", 0);
    GEMM_ITER(6, 0, "4", 0);
    GEMM_ITER(7, 1, "0", 0);

#undef GEMM_ITER
#undef STAGE_KT

    // ---- epilogue: label-free neg-part sum, 3 VALU/elem ----
    float lsum = 0.f;
#pragma unroll
    for (int r = 0; r < 16; ++r) {
        float s;
        s = acc00[r]; lsum += (s > MARGINF) ? s : 0.0f;
        s = acc01[r]; lsum += (s > MARGINF) ? s : 0.0f;
        s = acc10[r]; lsum += (s > MARGINF) ? s : 0.0f;
        s = acc11[r]; lsum += (s > MARGINF) ? s : 0.0f;
    }
    // off-diagonal block-tiles count twice (symmetry); diag tiles: full-block
    // sum == 2*strict-upper + diagonal (s symmetric within diag block)
    if (bi != bj) lsum *= 2.0f;

    // wave reduce then cross-wave
#pragma unroll
    for (int mask = 1; mask < 64; mask <<= 1) lsum += __shfl_xor(lsum, mask, 64);
    if (lane == 0) redbuf[wid] = lsum;
    __syncthreads();
    if (tid == 0)
        partials[p] = (double)(redbuf[0] + redbuf[1] + redbuf[2] + redbuf[3]);
}

// ---------- pass 3: sparse same-label correction ----------
// One block per label: gather rows with this label, for every ordered pair
// (incl. i==j) compute bf16 dot (consistent with GEMM values) and accumulate
// posv(s) - negv(s).
__global__ void __launch_bounds__(256) samepair_k(const unsigned short* __restrict__ xb,
                                                  const int* __restrict__ tg,
                                                  double* __restrict__ partials2) {
    const int lbl = blockIdx.x;
    __shared__ int idx[96];
    __shared__ int cnt;
    __shared__ double dred[4];
    if (threadIdx.x == 0) cnt = 0;
    __syncthreads();
    for (int i = threadIdx.x; i < 8192; i += 256)
        if (tg[i] == lbl) { int q = atomicAdd(&cnt, 1); if (q < 96) idx[q] = i; }
    __syncthreads();
    int c = cnt; if (c > 96) c = 96;

    double dsum = 0.0;
    for (int t = threadIdx.x; t < c * c; t += 256) {
        const int i = idx[t / c], j = idx[t % c];
        const short8x* xi = (const short8x*)(xb + (size_t)i * 256);
        const short8x* xj = (const short8x*)(xb + (size_t)j * 256);
        float s = 0.f;
#pragma unroll 4
        for (int q = 0; q < 32; ++q) {
            short8x a = xi[q], b = xj[q];
#pragma unroll
            for (int e = 0; e < 8; ++e) {
                float fa = __uint_as_float(((unsigned int)(unsigned short)a[e]) << 16);
                float fb = __uint_as_float(((unsigned int)(unsigned short)b[e]) << 16);
                s = fmaf(fa, fb, s);
            }
        }
        const float posv = (s < 1.0f) ? (1.0f - s) : 0.0f;
        const float negv = (s > MARGINF) ? s : 0.0f;
        dsum += (double)(posv - negv);
    }

    // wave reduce then cross-wave
#pragma unroll
    for (int mask = 1; mask < 64; mask <<= 1) dsum += __shfl_xor(dsum, mask, 64);
    const int wid = threadIdx.x >> 6;
    if ((threadIdx.x & 63) == 0) dred[wid] = dsum;
    __syncthreads();
    if (threadIdx.x == 0)
        partials2[lbl] = dred[0] + dred[1] + dred[2] + dred[3];
}

// ---------- pass 4: sum partials (2080 gemm + 1000 sparse), divide by N ----------
__global__ void __launch_bounds__(256) finalize_k(const double* __restrict__ partials,
                                                  float* __restrict__ out) {
    double s = 0.0;
    for (int i = threadIdx.x; i < 3080; i += 256) s += partials[i];
#pragma unroll
    for (int mask = 1; mask < 64; mask <<= 1) s += __shfl_xor(s, mask, 64);
    __shared__ double red[4];
    const int wid = threadIdx.x >> 6;
    if ((threadIdx.x & 63) == 0) red[wid] = s;
    __syncthreads();
    if (threadIdx.x == 0)
        out[0] = (float)((red[0] + red[1] + red[2] + red[3]) / 8192.0);
}

extern "C" void kernel_launch(void* const* d_in, const int* in_sizes, int n_in,
                              void* d_out, int out_size, void* d_ws, size_t ws_size,
                              hipStream_t stream) {
    (void)in_sizes; (void)n_in; (void)out_size; (void)ws_size;
    const float* x  = (const float*)d_in[0];
    const int*   tg = (const int*)d_in[1];
    float* out = (float*)d_out;

    double* partials   = (double*)d_ws;                          // [0..2079] gemm
    double* partials2  = (double*)d_ws + 2080;                   // [2080..3079] sparse
    unsigned short* xb = (unsigned short*)((char*)d_ws + 32768); // 4MB bf16 X (row-major)

    convert_k<<<1024, 256, 0, stream>>>(x, xb);
    gemm_loss_k<<<2080, 256, 0, stream>>>(xb, partials);
    samepair_k<<<1000, 256, 0, stream>>>(xb, tg, partials2);
    finalize_k<<<1, 256, 0, stream>>>(partials, out);
}